// Round 23
// baseline (40.226 us; speedup 1.0000x reference)
//
#include <hip/hip_runtime.h>
#include <math.h>

// SparseMultiheadAttention B=2,H=16,S=2048,DH=64, STRIDE=128, EXPR=32, bidirectional.
// Mask factorization (HW-validated rounds 0-2):
//   allowed(i,c) = (c&127)>=96 | ((c&127)==0 && c>0) | ((c>>7)==a(i))
//   a(i) = (i>>7) - ((i&127)==0 && i>0)
// R23 = R22 with __syncthreads() replaced by a NO-VMCNT-DRAIN barrier:
//   s_waitcnt lgkmcnt(0)  (LDS-write visibility for the dbuf handoff)
//   s_barrier
// __syncthreads emits s_waitcnt vmcnt(0) lgkmcnt(0) (m97 note) which drains
// the 2-ahead pipeline's in-flight global loads AT EVERY BARRIER - they target
// registers only, so carrying them across is safe (T4: never drain vmcnt in
// the main loop). Single-variable probe: null result => compiler wasn't
// draining and the structure is at its floor.
// Kept from R22: no setprio; joint softmax everywhere; uniform 5-interval
// schedule with wave-0 self-staged s10/s11 tail; XCD swizzle
// sw=(bid&7)*64+(bid>>3) (FETCH 24.7MB); 2-ahead pipeline (load(I+2) ->
// compute(I) -> write(I+1) -> pack(I+2) -> barrier, none after last);
// exp2-domain softmax (log2e in Q pre-scale, THR 11.5); P in registers
// (swapped QK^T -> lane owns 16x16x16 A-frag); V swz ^((d&15)<<3) (odd rows
// as 2xb64); K swz ^(c&7)<<4; LDS 64KB = 2 bufs x (K 2x8K + V 2x8K);
// 512-thr blocks, grid 512.
// Sub-segments (A = R, block rows [128R,128R+128)):
//   s0..7 : summary pairs [256s+96,+128) u [256s+224,+256)       no mask
//   s8    : local [128A, +64)                                     mask a_row==A
//   s9    : local [128A+64,+96) (32) + checkpoints {128k,k=1..15}+pad (16), nn=3
//   s10/11: special block A-1 (R > 0 only); wave-0 self-staged post-loop.
// Coverage verified per-row (col 128A masked in checkpoint tile, unmasked in s8;
// col 128(A-1) masked in checkpoint tile for special row, unmasked in s10).

namespace {

constexpr int kS = 2048, kD = 64;

typedef __attribute__((ext_vector_type(8))) short short8;
typedef __attribute__((ext_vector_type(4))) short short4b;
typedef __attribute__((ext_vector_type(4))) float f32x4;
typedef __attribute__((ext_vector_type(4))) unsigned int u32x4;
typedef __attribute__((ext_vector_type(2))) unsigned int u32x2;

template <int N> struct IC { static constexpr int value = N; };

__device__ __forceinline__ void barrier_nodrain() {
    // LDS visibility only; in-flight global (register) loads stay pending.
    asm volatile("s_waitcnt lgkmcnt(0)" ::: "memory");
    __builtin_amdgcn_s_barrier();
}

__device__ __forceinline__ float fexp2(float x) {   // raw v_exp_f32
#if __has_builtin(__builtin_amdgcn_exp2f)
    return __builtin_amdgcn_exp2f(x);
#else
    return exp2f(x);
#endif
}

__device__ __forceinline__ unsigned f2bf(float f) {           // RNE (Q only)
    unsigned u = __builtin_bit_cast(unsigned, f);
    u += 0x7fffu + ((u >> 16) & 1u);
    return u >> 16;
}
__device__ __forceinline__ unsigned pk2(float a, float b) {   // RNE pair
    return f2bf(a) | (f2bf(b) << 16);
}
__device__ __forceinline__ unsigned pkt(float a, float b) {   // truncating pair: 1 v_perm
    return __builtin_amdgcn_perm(__builtin_bit_cast(unsigned, b),
                                 __builtin_bit_cast(unsigned, a), 0x07060302u);
}

__device__ __forceinline__ f32x4 mfma32(short8 a, short8 b, f32x4 c) {
    return __builtin_amdgcn_mfma_f32_16x16x32_bf16(a, b, c, 0, 0, 0);
}
#if __has_builtin(__builtin_amdgcn_mfma_f32_16x16x16bf16_1k)
__device__ __forceinline__ f32x4 mfma16(short4b a, short4b b, f32x4 c) {
    return __builtin_amdgcn_mfma_f32_16x16x16bf16_1k(a, b, c, 0, 0, 0);
}
#else
__device__ __forceinline__ f32x4 mfma16(short4b a, short4b b, f32x4 c) {
    asm volatile("v_mfma_f32_16x16x16_bf16 %0, %1, %2, %0"
                 : "+v"(c) : "v"(a), "v"(b));
    return c;
}
#endif

__device__ __forceinline__ int seglen(int s) { return s == 9 ? 48 : (s == 11 ? 32 : 64); }

__device__ __forceinline__ int colOf(int s, int p, int A) {
    if (s < 8)  return 256 * s + (p < 32 ? 96 + p : 192 + p);
    if (s == 8) return 128 * A + p;
    if (s == 9) {
        if (p < 32) return 128 * A + 64 + p;
        const int k = p - 31;                 // 1..16
        return k < 16 ? 128 * k : 2047;       // p=47 pad (always masked)
    }
    if (s == 10) return 128 * (A - 1) + p;
    return 128 * (A - 1) + 64 + p;            // s==11
}

__global__ __launch_bounds__(512) void sparse_attn21(
    const float* __restrict__ Q, const float* __restrict__ K,
    const float* __restrict__ V, float* __restrict__ Out)
{
    // buf b at b*32768: K sub-seg u at +u*8192 (swz ^(c&7)<<4),
    //                   V sub-seg u at +16384+u*8192 (swz ^((d&15)<<3))
    __shared__ __align__(16) unsigned char lds[65536];

    const int tid = threadIdx.x;
    const int wv = tid >> 6;                     // 0..7
    const int l = tid & 63, g = l >> 4, lm = l & 15;
    // XCD swizzle: each XCD (bid&7) gets 64 consecutive logical blocks =
    // 4 complete bh's -> their summary K/V (~4MB) fits that XCD's L2.
    const int bid = blockIdx.x;
    const int sw  = (bid & 7) * 64 + (bid >> 3);   // bijective on [0,512)
    const int bh = sw >> 4, R = sw & 15;
    const int A = R;
    const int rowbase = R * 128 + wv * 16;       // wave owns 16 rows
    const bool spec = (R > 0);
    constexpr int nI = 5;                        // uniform

    const float* Qb = Q + (size_t)bh * kS * kD;
    const float* Kb = K + (size_t)bh * kS * kD;
    const float* Vb = V + (size_t)bh * kS * kD;

    // Q fragment (mfma B-operand in swapped QK: col=q=lm, k=d=g*8+j+32kk)
    // pre-scale = (1/8) * log2(e): scores land directly in exp2 domain
    constexpr float kQScale = 0.125f * 1.4426950408889634f;
    short8 qa[2];
#pragma unroll
    for (int kk = 0; kk < 2; ++kk) {
        const float* qp = Qb + (size_t)(rowbase + lm) * kD + kk*32 + g*8;
        float4 a = *(const float4*)qp;
        float4 b = *(const float4*)(qp + 4);
        u32x4 t;
        t.x = pk2(a.x*kQScale, a.y*kQScale);
        t.y = pk2(a.z*kQScale, a.w*kQScale);
        t.z = pk2(b.x*kQScale, b.y*kQScale);
        t.w = pk2(b.z*kQScale, b.w*kQScale);
        qa[kk] = __builtin_bit_cast(short8, t);
    }

    // a-value for this lane's q-row (q = rowbase + lm)
    const int qrow = rowbase + lm;
    const int aq = (qrow >> 7) - (((qrow & 127) == 0 && qrow > 0) ? 1 : 0);

    float mrun = -1e30f, lpar = 0.f;   // softmax state (log2 domain) for q = lm
    f32x4 o[4];                         // O[q=4g+i][d=lm+16nv]
#pragma unroll
    for (int nv = 0; nv < 4; ++nv) o[nv] = (f32x4){0.f,0.f,0.f,0.f};

    // staging: thread-group (tid>>8) owns sub-seg u = group of each interval
    const int group = tid >> 8;                  // 0 or 1
    const int tid_g = tid & 255;
    const int kc  = tid_g >> 2,  kq4 = tid_g & 3;
    const int vc0 = (tid_g >> 5) * 8, vd0 = (tid_g & 31) * 2;

    float4 kreg[4];                      // fp32 in flight (across barriers now)
    float2 vreg[8];
    u32x4  kp0, kp1;                     // packed bf16, held ACROSS the barrier
    u32x4  vp0;
    u32x2  vp1a, vp1b;

    auto stage_load = [&](int I) {       // issue global loads only (s<10 only)
        const int s = 2*I + group;
        if (s >= 10) return;
        const int len = seglen(s);
        if (kc < len) {
            const float* kp = Kb + (size_t)colOf(s, kc, A) * kD + kq4*16;
            kreg[0] = *(const float4*)(kp);
            kreg[1] = *(const float4*)(kp + 4);
            kreg[2] = *(const float4*)(kp + 8);
            kreg[3] = *(const float4*)(kp + 12);
        }
        if (vc0 < len) {
#pragma unroll
            for (int j = 0; j < 8; ++j)
                vreg[j] = *(const float2*)(Vb + (size_t)colOf(s, vc0 + j, A) * kD + vd0);
        }
    };

    auto stage_pack = [&](int I) {       // vmcnt waits land here (covered by compute)
        const int s = 2*I + group;
        if (s >= 10) return;
        const int len = seglen(s);
        if (kc < len) {
            kp0.x = pkt(kreg[0].x,kreg[0].y); kp0.y = pkt(kreg[0].z,kreg[0].w);
            kp0.z = pkt(kreg[1].x,kreg[1].y); kp0.w = pkt(kreg[1].z,kreg[1].w);
            kp1.x = pkt(kreg[2].x,kreg[2].y); kp1.y = pkt(kreg[2].z,kreg[2].w);
            kp1.z = pkt(kreg[3].x,kreg[3].y); kp1.w = pkt(kreg[3].z,kreg[3].w);
        }
        if (vc0 < len) {
            vp0.x = pkt(vreg[0].x,vreg[1].x); vp0.y = pkt(vreg[2].x,vreg[3].x);
            vp0.z = pkt(vreg[4].x,vreg[5].x); vp0.w = pkt(vreg[6].x,vreg[7].x);
            vp1a.x = pkt(vreg[0].y,vreg[1].y); vp1a.y = pkt(vreg[2].y,vreg[3].y);
            vp1b.x = pkt(vreg[4].y,vreg[5].y); vp1b.y = pkt(vreg[6].y,vreg[7].y);
        }
    };

    auto stage_write = [&](int I, int buf) {   // LDS writes from packed regs only
        const int s = 2*I + group;
        if (s >= 10) return;
        unsigned char* ksb = lds + buf * 32768 + group * 8192;
        unsigned char* vsb = lds + buf * 32768 + 16384 + group * 8192;
        const int len = seglen(s);
        if (kc < len) {
            const unsigned b  = (unsigned)(kc*128 + kq4*32);
            const unsigned sw2 = ((unsigned)(kc & 7)) << 4;
            *(u32x4*)(ksb + (b ^ sw2))        = kp0;
            *(u32x4*)(ksb + ((b ^ sw2) ^ 16)) = kp1;
        }
        if (vc0 < len) {
            // even row vd0: swz multiple of 16 -> contiguous b128 is exact
            const unsigned swe = ((unsigned)(vd0 & 15)) << 3;
            *(u32x4*)(vsb + ((unsigned)(vd0*128 + vc0*2) ^ swe)) = vp0;
            // odd row vd0+1: swz has bit 3 -> two b64 chunks (XOR exact at 8B)
            const unsigned swo = ((unsigned)((vd0 + 1) & 15)) << 3;
            *(u32x2*)(vsb + ((unsigned)((vd0+1)*128 + vc0*2)     ^ swo)) = vp1a;
            *(u32x2*)(vsb + ((unsigned)((vd0+1)*128 + vc0*2 + 8) ^ swo)) = vp1b;
        }
    };

    // --- QK tiles for one subsegment into sf (compile-time nn) --------------
    auto qk = [&](const unsigned char* ksb, f32x4 (&sf)[4], auto NNC) {
        constexpr int nn = decltype(NNC)::value;
#pragma unroll
        for (int n = 0; n < nn; ++n) {
            const int c = lm + 16*n;
#pragma unroll
            for (int kk = 0; kk < 2; ++kk) {
                const unsigned byte = (unsigned)(c*128 + kk*64 + g*16) ^ (((unsigned)(c & 7)) << 4);
                const short8 kf = *(const short8*)(ksb + byte);
                sf[n] = mfma32(kf, qa[kk], sf[n]);
            }
        }
    };

    // --- exp2+pack+PV for one subsegment (assumes mrun current) -------------
    auto exp_pv = [&](f32x4 (&sf)[4], const unsigned char* vsb, auto NNC) {
        constexpr int nn = decltype(NNC)::value;
        u32x2 pa[4];
        float psum = 0.f;
#pragma unroll
        for (int n = 0; n < nn; ++n) {
            const float p0 = fexp2(sf[n][0] - mrun);
            const float p1 = fexp2(sf[n][1] - mrun);
            const float p2 = fexp2(sf[n][2] - mrun);
            const float p3 = fexp2(sf[n][3] - mrun);
            psum += (p0 + p1) + (p2 + p3);
            pa[n].x = pkt(p0, p1);
            pa[n].y = pkt(p2, p3);
        }
        lpar += psum;
#pragma unroll
        for (int nv = 0; nv < 4; ++nv) {
            const int d = lm + 16*nv;
            const unsigned dsw = ((unsigned)(d & 15)) << 3;
#pragma unroll
            for (int n = 0; n < nn; ++n) {
                const unsigned byte = ((unsigned)(d*128 + 32*n + 8*g)) ^ dsw;
                const short4b vb = *(const short4b*)(vsb + byte);
                o[nv] = mfma16(__builtin_bit_cast(short4b, pa[n]), vb, o[nv]);
            }
        }
    };

    // rescale helper: update mrun/lpar/o given tile max t (defer-max THR=11.5)
    auto rescale = [&](float t) {
        const bool need = t > mrun + 11.5f;
        if (__any(need)) {
            const float nm = fmaxf(mrun, t);
            const float al = fexp2(mrun - nm);
            mrun = nm; lpar *= al;
#pragma unroll
            for (int i = 0; i < 4; ++i) {    // redistribute al to C-layout rows
                const float ali = __shfl(al, (g*4 + i) + 16*g);
#pragma unroll
                for (int nv = 0; nv < 4; ++nv) o[nv][i] *= ali;
            }
        }
    };

    // --- fast path: I=0..3 (s=0..7), branch-free, QK mixed, JOINT softmax ---
    auto compute_fast = [&](int buf) {
        const unsigned char* base = lds + buf * 32768;
        const unsigned char* ksb0 = base;
        const unsigned char* ksb1 = base + 8192;
        const unsigned char* vsb0 = base + 16384;
        const unsigned char* vsb1 = base + 24576;

        f32x4 sf0[4], sf1[4];
#pragma unroll
        for (int n = 0; n < 4; ++n) {
            sf0[n] = (f32x4){0.f,0.f,0.f,0.f};
            sf1[n] = (f32x4){0.f,0.f,0.f,0.f};
        }
#pragma unroll
        for (int n = 0; n < 4; ++n) {
            const int c = lm + 16*n;
#pragma unroll
            for (int kk = 0; kk < 2; ++kk) {
                const unsigned byte = (unsigned)(c*128 + kk*64 + g*16) ^ (((unsigned)(c & 7)) << 4);
                const short8 kf0 = *(const short8*)(ksb0 + byte);
                const short8 kf1 = *(const short8*)(ksb1 + byte);
                sf0[n] = mfma32(kf0, qa[kk], sf0[n]);
                sf1[n] = mfma32(kf1, qa[kk], sf1[n]);
            }
        }

        // joint max over both subsegments (128-col tile): ONE cross-lane reduce
        float t = -1e30f;
#pragma unroll
        for (int n = 0; n < 4; ++n) {
            t = fmaxf(t, fmaxf(fmaxf(sf0[n][0], sf0[n][1]), fmaxf(sf0[n][2], sf0[n][3])));
            t = fmaxf(t, fmaxf(fmaxf(sf1[n][0], sf1[n][1]), fmaxf(sf1[n][2], sf1[n][3])));
        }
        t = fmaxf(t, __shfl_xor(t, 16));
        t = fmaxf(t, __shfl_xor(t, 32));
        rescale(t);
        exp_pv(sf0, vsb0, IC<4>{});
        exp_pv(sf1, vsb1, IC<4>{});
    };

    // --- interval 4 (s8 + s9): JOINT softmax across both subsegs ------------
    auto compute_gen2 = [&](int buf) {
        const unsigned char* base = lds + buf * 32768;
        f32x4 sf8[4], sf9[4];
#pragma unroll
        for (int n = 0; n < 4; ++n) {
            sf8[n] = (f32x4){0.f,0.f,0.f,0.f};
            sf9[n] = (f32x4){0.f,0.f,0.f,0.f};
        }
        qk(base,        sf8, IC<4>{});
        qk(base + 8192, sf9, IC<3>{});

        // masks: s8 -> aq==A (all cols); s9 -> local(aq==A) / checkpoint tile
#pragma unroll
        for (int n = 0; n < 4; ++n)
#pragma unroll
        for (int i = 0; i < 4; ++i)
            if (aq != A) sf8[n][i] = -1e30f;
#pragma unroll
        for (int n = 0; n < 3; ++n)
#pragma unroll
        for (int i = 0; i < 4; ++i) {
            const int c = 16*n + g*4 + i;
            const bool ok = (c < 32) ? (aq == A) : (c < 47 && aq != (c - 31));
            if (!ok) sf9[n][i] = -1e30f;
        }

        float t = -1e30f;
#pragma unroll
        for (int n = 0; n < 4; ++n)
            t = fmaxf(t, fmaxf(fmaxf(sf8[n][0], sf8[n][1]), fmaxf(sf8[n][2], sf8[n][3])));
#pragma unroll
        for (int n = 0; n < 3; ++n)
            t = fmaxf(t, fmaxf(fmaxf(sf9[n][0], sf9[n][1]), fmaxf(sf9[n][2], sf9[n][3])));
        t = fmaxf(t, __shfl_xor(t, 16));
        t = fmaxf(t, __shfl_xor(t, 32));
        rescale(t);
        exp_pv(sf8, base + 16384, IC<4>{});
        exp_pv(sf9, base + 24576, IC<3>{});
    };

    // prologue: interval 0 fully staged; interval 1 loaded+packed (in regs)
    stage_load(0); stage_pack(0); stage_write(0, 0);
    stage_load(1); stage_pack(1);
    barrier_nodrain();

    for (int I = 0; I < nI; ++I) {
        if (I + 2 < nI) stage_load(I + 2);                // issue 2 ahead
        if (I < 4) compute_fast(I & 1);                   // covers load latency
        else       compute_gen2(I & 1);
        if (I + 1 < nI) stage_write(I + 1, (I + 1) & 1);  // T14: write LATE
        if (I + 2 < nI) stage_pack(I + 2);                // vmcnt wait ~free here
        if (I + 1 < nI) barrier_nodrain();                // none after LAST;
        // no vmcnt drain: in-flight register loads survive the barrier (T4)
    }

    // --- special block s10/s11: wave 0 self-stages buf 1 (quiet since
    // barrier-3: compute(4) uses buf 0, no block stage_write targets buf 1),
    // then computes with NO barrier (within-wave LDS RAW is lgkmcnt-ordered).
    if (spec && wv == 0) {
#pragma unroll
        for (int ss = 0; ss < 2; ++ss) {
            const int s = 10 + ss;
            const int len = (ss == 0) ? 64 : 32;
            unsigned char* ksb = lds + 32768 + ss * 8192;
            unsigned char* vsb = lds + 32768 + 16384 + ss * 8192;
            // K: lane l = column c, 4 quarters of 16 d-floats
            const int c = l;
            if (c < len) {
                const int col = colOf(s, c, A);
                const float* kp = Kb + (size_t)col * kD;
                const unsigned sw2 = ((unsigned)(c & 7)) << 4;
#pragma unroll
                for (int q4 = 0; q4 < 4; ++q4) {
                    float4 k0 = *(const float4*)(kp + q4*16);
                    float4 k1 = *(const float4*)(kp + q4*16 + 4);
                    float4 k2 = *(const float4*)(kp + q4*16 + 8);
                    float4 k3 = *(const float4*)(kp + q4*16 + 12);
                    u32x4 lo, hi;
                    lo.x = pkt(k0.x,k0.y); lo.y = pkt(k0.z,k0.w);
                    lo.z = pkt(k1.x,k1.y); lo.w = pkt(k1.z,k1.w);
                    hi.x = pkt(k2.x,k2.y); hi.y = pkt(k2.z,k2.w);
                    hi.z = pkt(k3.x,k3.y); hi.w = pkt(k3.z,k3.w);
                    const unsigned b = (unsigned)(c*128 + q4*32);
                    *(u32x4*)(ksb + (b ^ sw2))        = lo;
                    *(u32x4*)(ksb + ((b ^ sw2) ^ 16)) = hi;
                }
            }
            // V^T: lane l -> c0=(l>>3)*8, dbase=(l&7)*2, 4 d-strips of 2 rows
            const int c0s = (l >> 3) * 8;
            if (c0s < len) {
#pragma unroll
                for (int dd = 0; dd < 4; ++dd) {
                    const int d0 = (l & 7) * 2 + 16 * dd;
                    float2 r[8];
#pragma unroll
                    for (int j = 0; j < 8; ++j)
                        r[j] = *(const float2*)(Vb + (size_t)colOf(s, c0s + j, A) * kD + d0);
                    u32x4 t0; u32x2 t1a, t1b;
                    t0.x = pkt(r[0].x,r[1].x); t0.y = pkt(r[2].x,r[3].x);
                    t0.z = pkt(r[4].x,r[5].x); t0.w = pkt(r[6].x,r[7].x);
                    t1a.x = pkt(r[0].y,r[1].y); t1a.y = pkt(r[2].y,r[3].y);
                    t1b.x = pkt(r[4].y,r[5].y); t1b.y = pkt(r[6].y,r[7].y);
                    const unsigned swe = ((unsigned)(d0 & 15)) << 3;
                    *(u32x4*)(vsb + ((unsigned)(d0*128 + c0s*2) ^ swe)) = t0;
                    const unsigned swo = ((unsigned)((d0 + 1) & 15)) << 3;
                    *(u32x2*)(vsb + ((unsigned)((d0+1)*128 + c0s*2)     ^ swo)) = t1a;
                    *(u32x2*)(vsb + ((unsigned)((d0+1)*128 + c0s*2 + 8) ^ swo)) = t1b;
                }
            }
        }
        asm volatile("s_waitcnt lgkmcnt(0)" ::: "memory");

        // JOINT s10+s11: one max/rescale; mask is row-only (aq == A-1)
        f32x4 sfa[4], sfb[4];
#pragma unroll
        for (int n = 0; n < 4; ++n) {
            sfa[n] = (f32x4){0.f,0.f,0.f,0.f};
            sfb[n] = (f32x4){0.f,0.f,0.f,0.f};
        }
        qk(lds + 32768,        sfa, IC<4>{});
        qk(lds + 32768 + 8192, sfb, IC<2>{});
        if (aq != A - 1) {
#pragma unroll
            for (int n = 0; n < 4; ++n)
#pragma unroll
            for (int i = 0; i < 4; ++i) sfa[n][i] = -1e30f;
#pragma unroll
            for (int n = 0; n < 2; ++n)
#pragma unroll
            for (int i = 0; i < 4; ++i) sfb[n][i] = -1e30f;
        }
        float t = -1e30f;
#pragma unroll
        for (int n = 0; n < 4; ++n)
            t = fmaxf(t, fmaxf(fmaxf(sfa[n][0], sfa[n][1]), fmaxf(sfa[n][2], sfa[n][3])));
#pragma unroll
        for (int n = 0; n < 2; ++n)
            t = fmaxf(t, fmaxf(fmaxf(sfb[n][0], sfb[n][1]), fmaxf(sfb[n][2], sfb[n][3])));
        t = fmaxf(t, __shfl_xor(t, 16));
        t = fmaxf(t, __shfl_xor(t, 32));
        rescale(t);
        exp_pv(sfa, lds + 32768 + 16384, IC<4>{});
        exp_pv(sfb, lds + 32768 + 24576, IC<2>{});
    }

    // epilogue: total row sum for q=lm, redistribute 1/l to C-layout rows, store
    float v = lpar;
    v += __shfl_xor(v, 16);
    v += __shfl_xor(v, 32);
    const float linv = 1.f / v;
#pragma unroll
    for (int i = 0; i < 4; ++i) {
        const float inv = __shfl(linv, (g*4 + i) + 16*g);
        float* op = Out + ((size_t)bh * kS + rowbase + g*4 + i) * kD + lm;
#pragma unroll
        for (int nv = 0; nv < 4; ++nv)
            op[16*nv] = o[nv][i] * inv;
    }
}

} // namespace

extern "C" void kernel_launch(void* const* d_in, const int* in_sizes, int n_in,
                              void* d_out, int out_size, void* d_ws, size_t ws_size,
                              hipStream_t stream) {
    const float* q = (const float*)d_in[0];
    const float* k = (const float*)d_in[1];
    const float* v = (const float*)d_in[2];
    // d_in[3] (mask) is a pure function of (S,STRIDE,EXPR) reproduced in-kernel.
    float* out = (float*)d_out;
    dim3 grid(512), block(512);
    hipLaunchKernelGGL(sparse_attn21, grid, block, 0, stream, q, k, v, out);
}

// Round 24
// 39.612 us; speedup vs baseline: 1.0155x; 1.0155x over previous
//
#include <hip/hip_runtime.h>
#include <math.h>

// SparseMultiheadAttention B=2,H=16,S=2048,DH=64, STRIDE=128, EXPR=32, bidirectional.
// FINAL (R24 = R22 verbatim, the best-measured kernel at 39.7us; R23's
// no-drain-barrier probe was null-to-negative -- its "memory" clobbers forced
// ~7MB of scratch traffic -- so it is reverted).
// Mask factorization (HW-validated rounds 0-2):
//   allowed(i,c) = (c&127)>=96 | ((c&127)==0 && c>0) | ((c>>7)==a(i))
//   a(i) = (i>>7) - ((i&127)==0 && i>0)
// Design: 512-thr blocks (8 waves, 128 rows), grid 512; uniform 5-interval
// schedule; 2 x 64-col subsegments per interval; 2-ahead pipeline (load(I+2)
// -> compute(I) -> write(I+1) -> pack(I+2) -> barrier, none after last);
// JOINT softmax per interval; exp2-domain softmax (log2e folded into Q
// pre-scale, defer-max THR=11.5); swapped QK^T (lane owns a full q-row ->
// softmax state scalar; P stays in registers as the 16x16x16 MFMA A-frag);
// PV via mfma16 straight from registers; wave-0 self-staged s10/s11 tail
// (no barrier); XCD swizzle sw=(bid&7)*64+(bid>>3) (4 complete bh per XCD ->
// L2-resident K/V, FETCH 65.6->24.7MB); V swz ^((d&15)<<3) (odd rows stored
// as 2xb64 -- 16B stores only commute with swizzle bits >=16); K swz
// ^(c&7)<<4; LDS 64KB = 2 bufs x (K 2x8K + V 2x8K); no s_setprio (negative
// on barrier-lockstep waves, m190).
// Sub-segments (A = R, block rows [128R,128R+128)):
//   s0..7 : summary pairs [256s+96,+128) u [256s+224,+256)       no mask
//   s8    : local [128A, +64)                                     mask a_row==A
//   s9    : local [128A+64,+96) (32) + checkpoints {128k,k=1..15}+pad (16), nn=3
//   s10/11: special block A-1 (R > 0 only); wave-0 self-staged post-loop.
// Coverage verified per-row (col 128A masked in checkpoint tile, unmasked in s8;
// col 128(A-1) masked in checkpoint tile for special row, unmasked in s10).

namespace {

constexpr int kS = 2048, kD = 64;

typedef __attribute__((ext_vector_type(8))) short short8;
typedef __attribute__((ext_vector_type(4))) short short4b;
typedef __attribute__((ext_vector_type(4))) float f32x4;
typedef __attribute__((ext_vector_type(4))) unsigned int u32x4;
typedef __attribute__((ext_vector_type(2))) unsigned int u32x2;

template <int N> struct IC { static constexpr int value = N; };

__device__ __forceinline__ float fexp2(float x) {   // raw v_exp_f32
#if __has_builtin(__builtin_amdgcn_exp2f)
    return __builtin_amdgcn_exp2f(x);
#else
    return exp2f(x);
#endif
}

__device__ __forceinline__ unsigned f2bf(float f) {           // RNE (Q only)
    unsigned u = __builtin_bit_cast(unsigned, f);
    u += 0x7fffu + ((u >> 16) & 1u);
    return u >> 16;
}
__device__ __forceinline__ unsigned pk2(float a, float b) {   // RNE pair
    return f2bf(a) | (f2bf(b) << 16);
}
__device__ __forceinline__ unsigned pkt(float a, float b) {   // truncating pair: 1 v_perm
    return __builtin_amdgcn_perm(__builtin_bit_cast(unsigned, b),
                                 __builtin_bit_cast(unsigned, a), 0x07060302u);
}

__device__ __forceinline__ f32x4 mfma32(short8 a, short8 b, f32x4 c) {
    return __builtin_amdgcn_mfma_f32_16x16x32_bf16(a, b, c, 0, 0, 0);
}
#if __has_builtin(__builtin_amdgcn_mfma_f32_16x16x16bf16_1k)
__device__ __forceinline__ f32x4 mfma16(short4b a, short4b b, f32x4 c) {
    return __builtin_amdgcn_mfma_f32_16x16x16bf16_1k(a, b, c, 0, 0, 0);
}
#else
__device__ __forceinline__ f32x4 mfma16(short4b a, short4b b, f32x4 c) {
    asm volatile("v_mfma_f32_16x16x16_bf16 %0, %1, %2, %0"
                 : "+v"(c) : "v"(a), "v"(b));
    return c;
}
#endif

__device__ __forceinline__ int seglen(int s) { return s == 9 ? 48 : (s == 11 ? 32 : 64); }

__device__ __forceinline__ int colOf(int s, int p, int A) {
    if (s < 8)  return 256 * s + (p < 32 ? 96 + p : 192 + p);
    if (s == 8) return 128 * A + p;
    if (s == 9) {
        if (p < 32) return 128 * A + 64 + p;
        const int k = p - 31;                 // 1..16
        return k < 16 ? 128 * k : 2047;       // p=47 pad (always masked)
    }
    if (s == 10) return 128 * (A - 1) + p;
    return 128 * (A - 1) + 64 + p;            // s==11
}

__global__ __launch_bounds__(512) void sparse_attn22(
    const float* __restrict__ Q, const float* __restrict__ K,
    const float* __restrict__ V, float* __restrict__ Out)
{
    // buf b at b*32768: K sub-seg u at +u*8192 (swz ^(c&7)<<4),
    //                   V sub-seg u at +16384+u*8192 (swz ^((d&15)<<3))
    __shared__ __align__(16) unsigned char lds[65536];

    const int tid = threadIdx.x;
    const int wv = tid >> 6;                     // 0..7
    const int l = tid & 63, g = l >> 4, lm = l & 15;
    // XCD swizzle: each XCD (bid&7) gets 64 consecutive logical blocks =
    // 4 complete bh's -> their summary K/V (~4MB) fits that XCD's L2.
    const int bid = blockIdx.x;
    const int sw  = (bid & 7) * 64 + (bid >> 3);   // bijective on [0,512)
    const int bh = sw >> 4, R = sw & 15;
    const int A = R;
    const int rowbase = R * 128 + wv * 16;       // wave owns 16 rows
    const bool spec = (R > 0);
    constexpr int nI = 5;                        // uniform

    const float* Qb = Q + (size_t)bh * kS * kD;
    const float* Kb = K + (size_t)bh * kS * kD;
    const float* Vb = V + (size_t)bh * kS * kD;

    // Q fragment (mfma B-operand in swapped QK: col=q=lm, k=d=g*8+j+32kk)
    // pre-scale = (1/8) * log2(e): scores land directly in exp2 domain
    constexpr float kQScale = 0.125f * 1.4426950408889634f;
    short8 qa[2];
#pragma unroll
    for (int kk = 0; kk < 2; ++kk) {
        const float* qp = Qb + (size_t)(rowbase + lm) * kD + kk*32 + g*8;
        float4 a = *(const float4*)qp;
        float4 b = *(const float4*)(qp + 4);
        u32x4 t;
        t.x = pk2(a.x*kQScale, a.y*kQScale);
        t.y = pk2(a.z*kQScale, a.w*kQScale);
        t.z = pk2(b.x*kQScale, b.y*kQScale);
        t.w = pk2(b.z*kQScale, b.w*kQScale);
        qa[kk] = __builtin_bit_cast(short8, t);
    }

    // a-value for this lane's q-row (q = rowbase + lm)
    const int qrow = rowbase + lm;
    const int aq = (qrow >> 7) - (((qrow & 127) == 0 && qrow > 0) ? 1 : 0);

    float mrun = -1e30f, lpar = 0.f;   // softmax state (log2 domain) for q = lm
    f32x4 o[4];                         // O[q=4g+i][d=lm+16nv]
#pragma unroll
    for (int nv = 0; nv < 4; ++nv) o[nv] = (f32x4){0.f,0.f,0.f,0.f};

    // staging: thread-group (tid>>8) owns sub-seg u = group of each interval
    const int group = tid >> 8;                  // 0 or 1
    const int tid_g = tid & 255;
    const int kc  = tid_g >> 2,  kq4 = tid_g & 3;
    const int vc0 = (tid_g >> 5) * 8, vd0 = (tid_g & 31) * 2;

    float4 kreg[4];                      // fp32 in flight (intra-interval)
    float2 vreg[8];
    u32x4  kp0, kp1;                     // packed bf16, held ACROSS the barrier
    u32x4  vp0;
    u32x2  vp1a, vp1b;

    auto stage_load = [&](int I) {       // issue global loads only (s<10 only)
        const int s = 2*I + group;
        if (s >= 10) return;
        const int len = seglen(s);
        if (kc < len) {
            const float* kp = Kb + (size_t)colOf(s, kc, A) * kD + kq4*16;
            kreg[0] = *(const float4*)(kp);
            kreg[1] = *(const float4*)(kp + 4);
            kreg[2] = *(const float4*)(kp + 8);
            kreg[3] = *(const float4*)(kp + 12);
        }
        if (vc0 < len) {
#pragma unroll
            for (int j = 0; j < 8; ++j)
                vreg[j] = *(const float2*)(Vb + (size_t)colOf(s, vc0 + j, A) * kD + vd0);
        }
    };

    auto stage_pack = [&](int I) {       // vmcnt waits land here (covered by compute)
        const int s = 2*I + group;
        if (s >= 10) return;
        const int len = seglen(s);
        if (kc < len) {
            kp0.x = pkt(kreg[0].x,kreg[0].y); kp0.y = pkt(kreg[0].z,kreg[0].w);
            kp0.z = pkt(kreg[1].x,kreg[1].y); kp0.w = pkt(kreg[1].z,kreg[1].w);
            kp1.x = pkt(kreg[2].x,kreg[2].y); kp1.y = pkt(kreg[2].z,kreg[2].w);
            kp1.z = pkt(kreg[3].x,kreg[3].y); kp1.w = pkt(kreg[3].z,kreg[3].w);
        }
        if (vc0 < len) {
            vp0.x = pkt(vreg[0].x,vreg[1].x); vp0.y = pkt(vreg[2].x,vreg[3].x);
            vp0.z = pkt(vreg[4].x,vreg[5].x); vp0.w = pkt(vreg[6].x,vreg[7].x);
            vp1a.x = pkt(vreg[0].y,vreg[1].y); vp1a.y = pkt(vreg[2].y,vreg[3].y);
            vp1b.x = pkt(vreg[4].y,vreg[5].y); vp1b.y = pkt(vreg[6].y,vreg[7].y);
        }
    };

    auto stage_write = [&](int I, int buf) {   // LDS writes from packed regs only
        const int s = 2*I + group;
        if (s >= 10) return;
        unsigned char* ksb = lds + buf * 32768 + group * 8192;
        unsigned char* vsb = lds + buf * 32768 + 16384 + group * 8192;
        const int len = seglen(s);
        if (kc < len) {
            const unsigned b  = (unsigned)(kc*128 + kq4*32);
            const unsigned sw2 = ((unsigned)(kc & 7)) << 4;
            *(u32x4*)(ksb + (b ^ sw2))        = kp0;
            *(u32x4*)(ksb + ((b ^ sw2) ^ 16)) = kp1;
        }
        if (vc0 < len) {
            // even row vd0: swz multiple of 16 -> contiguous b128 is exact
            const unsigned swe = ((unsigned)(vd0 & 15)) << 3;
            *(u32x4*)(vsb + ((unsigned)(vd0*128 + vc0*2) ^ swe)) = vp0;
            // odd row vd0+1: swz has bit 3 -> two b64 chunks (XOR exact at 8B)
            const unsigned swo = ((unsigned)((vd0 + 1) & 15)) << 3;
            *(u32x2*)(vsb + ((unsigned)((vd0+1)*128 + vc0*2)     ^ swo)) = vp1a;
            *(u32x2*)(vsb + ((unsigned)((vd0+1)*128 + vc0*2 + 8) ^ swo)) = vp1b;
        }
    };

    // --- QK tiles for one subsegment into sf (compile-time nn) --------------
    auto qk = [&](const unsigned char* ksb, f32x4 (&sf)[4], auto NNC) {
        constexpr int nn = decltype(NNC)::value;
#pragma unroll
        for (int n = 0; n < nn; ++n) {
            const int c = lm + 16*n;
#pragma unroll
            for (int kk = 0; kk < 2; ++kk) {
                const unsigned byte = (unsigned)(c*128 + kk*64 + g*16) ^ (((unsigned)(c & 7)) << 4);
                const short8 kf = *(const short8*)(ksb + byte);
                sf[n] = mfma32(kf, qa[kk], sf[n]);
            }
        }
    };

    // --- exp2+pack+PV for one subsegment (assumes mrun current) -------------
    auto exp_pv = [&](f32x4 (&sf)[4], const unsigned char* vsb, auto NNC) {
        constexpr int nn = decltype(NNC)::value;
        u32x2 pa[4];
        float psum = 0.f;
#pragma unroll
        for (int n = 0; n < nn; ++n) {
            const float p0 = fexp2(sf[n][0] - mrun);
            const float p1 = fexp2(sf[n][1] - mrun);
            const float p2 = fexp2(sf[n][2] - mrun);
            const float p3 = fexp2(sf[n][3] - mrun);
            psum += (p0 + p1) + (p2 + p3);
            pa[n].x = pkt(p0, p1);
            pa[n].y = pkt(p2, p3);
        }
        lpar += psum;
#pragma unroll
        for (int nv = 0; nv < 4; ++nv) {
            const int d = lm + 16*nv;
            const unsigned dsw = ((unsigned)(d & 15)) << 3;
#pragma unroll
            for (int n = 0; n < nn; ++n) {
                const unsigned byte = ((unsigned)(d*128 + 32*n + 8*g)) ^ dsw;
                const short4b vb = *(const short4b*)(vsb + byte);
                o[nv] = mfma16(__builtin_bit_cast(short4b, pa[n]), vb, o[nv]);
            }
        }
    };

    // rescale helper: update mrun/lpar/o given tile max t (defer-max THR=11.5)
    auto rescale = [&](float t) {
        const bool need = t > mrun + 11.5f;
        if (__any(need)) {
            const float nm = fmaxf(mrun, t);
            const float al = fexp2(mrun - nm);
            mrun = nm; lpar *= al;
#pragma unroll
            for (int i = 0; i < 4; ++i) {    // redistribute al to C-layout rows
                const float ali = __shfl(al, (g*4 + i) + 16*g);
#pragma unroll
                for (int nv = 0; nv < 4; ++nv) o[nv][i] *= ali;
            }
        }
    };

    // --- fast path: I=0..3 (s=0..7), branch-free, QK mixed, JOINT softmax ---
    auto compute_fast = [&](int buf) {
        const unsigned char* base = lds + buf * 32768;
        const unsigned char* ksb0 = base;
        const unsigned char* ksb1 = base + 8192;
        const unsigned char* vsb0 = base + 16384;
        const unsigned char* vsb1 = base + 24576;

        f32x4 sf0[4], sf1[4];
#pragma unroll
        for (int n = 0; n < 4; ++n) {
            sf0[n] = (f32x4){0.f,0.f,0.f,0.f};
            sf1[n] = (f32x4){0.f,0.f,0.f,0.f};
        }
#pragma unroll
        for (int n = 0; n < 4; ++n) {
            const int c = lm + 16*n;
#pragma unroll
            for (int kk = 0; kk < 2; ++kk) {
                const unsigned byte = (unsigned)(c*128 + kk*64 + g*16) ^ (((unsigned)(c & 7)) << 4);
                const short8 kf0 = *(const short8*)(ksb0 + byte);
                const short8 kf1 = *(const short8*)(ksb1 + byte);
                sf0[n] = mfma32(kf0, qa[kk], sf0[n]);
                sf1[n] = mfma32(kf1, qa[kk], sf1[n]);
            }
        }

        // joint max over both subsegments (128-col tile): ONE cross-lane reduce
        float t = -1e30f;
#pragma unroll
        for (int n = 0; n < 4; ++n) {
            t = fmaxf(t, fmaxf(fmaxf(sf0[n][0], sf0[n][1]), fmaxf(sf0[n][2], sf0[n][3])));
            t = fmaxf(t, fmaxf(fmaxf(sf1[n][0], sf1[n][1]), fmaxf(sf1[n][2], sf1[n][3])));
        }
        t = fmaxf(t, __shfl_xor(t, 16));
        t = fmaxf(t, __shfl_xor(t, 32));
        rescale(t);
        exp_pv(sf0, vsb0, IC<4>{});
        exp_pv(sf1, vsb1, IC<4>{});
    };

    // --- interval 4 (s8 + s9): JOINT softmax across both subsegs ------------
    auto compute_gen2 = [&](int buf) {
        const unsigned char* base = lds + buf * 32768;
        f32x4 sf8[4], sf9[4];
#pragma unroll
        for (int n = 0; n < 4; ++n) {
            sf8[n] = (f32x4){0.f,0.f,0.f,0.f};
            sf9[n] = (f32x4){0.f,0.f,0.f,0.f};
        }
        qk(base,        sf8, IC<4>{});
        qk(base + 8192, sf9, IC<3>{});

        // masks: s8 -> aq==A (all cols); s9 -> local(aq==A) / checkpoint tile
#pragma unroll
        for (int n = 0; n < 4; ++n)
#pragma unroll
        for (int i = 0; i < 4; ++i)
            if (aq != A) sf8[n][i] = -1e30f;
#pragma unroll
        for (int n = 0; n < 3; ++n)
#pragma unroll
        for (int i = 0; i < 4; ++i) {
            const int c = 16*n + g*4 + i;
            const bool ok = (c < 32) ? (aq == A) : (c < 47 && aq != (c - 31));
            if (!ok) sf9[n][i] = -1e30f;
        }

        float t = -1e30f;
#pragma unroll
        for (int n = 0; n < 4; ++n)
            t = fmaxf(t, fmaxf(fmaxf(sf8[n][0], sf8[n][1]), fmaxf(sf8[n][2], sf8[n][3])));
#pragma unroll
        for (int n = 0; n < 3; ++n)
            t = fmaxf(t, fmaxf(fmaxf(sf9[n][0], sf9[n][1]), fmaxf(sf9[n][2], sf9[n][3])));
        t = fmaxf(t, __shfl_xor(t, 16));
        t = fmaxf(t, __shfl_xor(t, 32));
        rescale(t);
        exp_pv(sf8, base + 16384, IC<4>{});
        exp_pv(sf9, base + 24576, IC<3>{});
    };

    // prologue: interval 0 fully staged; interval 1 loaded+packed (in regs)
    stage_load(0); stage_pack(0); stage_write(0, 0);
    stage_load(1); stage_pack(1);
    __syncthreads();

    for (int I = 0; I < nI; ++I) {
        if (I + 2 < nI) stage_load(I + 2);                // issue 2 ahead
        if (I < 4) compute_fast(I & 1);                   // covers load latency
        else       compute_gen2(I & 1);
        if (I + 1 < nI) stage_write(I + 1, (I + 1) & 1);  // T14: write LATE
        if (I + 2 < nI) stage_pack(I + 2);                // vmcnt wait ~free here
        if (I + 1 < nI) __syncthreads();                  // none after LAST
    }

    // --- special block s10/s11: wave 0 self-stages buf 1 (quiet since
    // barrier-3: compute(4) uses buf 0, no block stage_write targets buf 1),
    // then computes with NO barrier (within-wave LDS RAW is lgkmcnt-ordered).
    if (spec && wv == 0) {
#pragma unroll
        for (int ss = 0; ss < 2; ++ss) {
            const int s = 10 + ss;
            const int len = (ss == 0) ? 64 : 32;
            unsigned char* ksb = lds + 32768 + ss * 8192;
            unsigned char* vsb = lds + 32768 + 16384 + ss * 8192;
            // K: lane l = column c, 4 quarters of 16 d-floats
            const int c = l;
            if (c < len) {
                const int col = colOf(s, c, A);
                const float* kp = Kb + (size_t)col * kD;
                const unsigned sw2 = ((unsigned)(c & 7)) << 4;
#pragma unroll
                for (int q4 = 0; q4 < 4; ++q4) {
                    float4 k0 = *(const float4*)(kp + q4*16);
                    float4 k1 = *(const float4*)(kp + q4*16 + 4);
                    float4 k2 = *(const float4*)(kp + q4*16 + 8);
                    float4 k3 = *(const float4*)(kp + q4*16 + 12);
                    u32x4 lo, hi;
                    lo.x = pkt(k0.x,k0.y); lo.y = pkt(k0.z,k0.w);
                    lo.z = pkt(k1.x,k1.y); lo.w = pkt(k1.z,k1.w);
                    hi.x = pkt(k2.x,k2.y); hi.y = pkt(k2.z,k2.w);
                    hi.z = pkt(k3.x,k3.y); hi.w = pkt(k3.z,k3.w);
                    const unsigned b = (unsigned)(c*128 + q4*32);
                    *(u32x4*)(ksb + (b ^ sw2))        = lo;
                    *(u32x4*)(ksb + ((b ^ sw2) ^ 16)) = hi;
                }
            }
            // V^T: lane l -> c0=(l>>3)*8, dbase=(l&7)*2, 4 d-strips of 2 rows
            const int c0s = (l >> 3) * 8;
            if (c0s < len) {
#pragma unroll
                for (int dd = 0; dd < 4; ++dd) {
                    const int d0 = (l & 7) * 2 + 16 * dd;
                    float2 r[8];
#pragma unroll
                    for (int j = 0; j < 8; ++j)
                        r[j] = *(const float2*)(Vb + (size_t)colOf(s, c0s + j, A) * kD + d0);
                    u32x4 t0; u32x2 t1a, t1b;
                    t0.x = pkt(r[0].x,r[1].x); t0.y = pkt(r[2].x,r[3].x);
                    t0.z = pkt(r[4].x,r[5].x); t0.w = pkt(r[6].x,r[7].x);
                    t1a.x = pkt(r[0].y,r[1].y); t1a.y = pkt(r[2].y,r[3].y);
                    t1b.x = pkt(r[4].y,r[5].y); t1b.y = pkt(r[6].y,r[7].y);
                    const unsigned swe = ((unsigned)(d0 & 15)) << 3;
                    *(u32x4*)(vsb + ((unsigned)(d0*128 + c0s*2) ^ swe)) = t0;
                    const unsigned swo = ((unsigned)((d0 + 1) & 15)) << 3;
                    *(u32x2*)(vsb + ((unsigned)((d0+1)*128 + c0s*2)     ^ swo)) = t1a;
                    *(u32x2*)(vsb + ((unsigned)((d0+1)*128 + c0s*2 + 8) ^ swo)) = t1b;
                }
            }
        }
        asm volatile("s_waitcnt lgkmcnt(0)" ::: "memory");

        // JOINT s10+s11: one max/rescale; mask is row-only (aq == A-1)
        f32x4 sfa[4], sfb[4];
#pragma unroll
        for (int n = 0; n < 4; ++n) {
            sfa[n] = (f32x4){0.f,0.f,0.f,0.f};
            sfb[n] = (f32x4){0.f,0.f,0.f,0.f};
        }
        qk(lds + 32768,        sfa, IC<4>{});
        qk(lds + 32768 + 8192, sfb, IC<2>{});
        if (aq != A - 1) {
#pragma unroll
            for (int n = 0; n < 4; ++n)
#pragma unroll
            for (int i = 0; i < 4; ++i) sfa[n][i] = -1e30f;
#pragma unroll
            for (int n = 0; n < 2; ++n)
#pragma unroll
            for (int i = 0; i < 4; ++i) sfb[n][i] = -1e30f;
        }
        float t = -1e30f;
#pragma unroll
        for (int n = 0; n < 4; ++n)
            t = fmaxf(t, fmaxf(fmaxf(sfa[n][0], sfa[n][1]), fmaxf(sfa[n][2], sfa[n][3])));
#pragma unroll
        for (int n = 0; n < 2; ++n)
            t = fmaxf(t, fmaxf(fmaxf(sfb[n][0], sfb[n][1]), fmaxf(sfb[n][2], sfb[n][3])));
        t = fmaxf(t, __shfl_xor(t, 16));
        t = fmaxf(t, __shfl_xor(t, 32));
        rescale(t);
        exp_pv(sfa, lds + 32768 + 16384, IC<4>{});
        exp_pv(sfb, lds + 32768 + 24576, IC<2>{});
    }

    // epilogue: total row sum for q=lm, redistribute 1/l to C-layout rows, store
    float v = lpar;
    v += __shfl_xor(v, 16);
    v += __shfl_xor(v, 32);
    const float linv = 1.f / v;
#pragma unroll
    for (int i = 0; i < 4; ++i) {
        const float inv = __shfl(linv, (g*4 + i) + 16*g);
        float* op = Out + ((size_t)bh * kS + rowbase + g*4 + i) * kD + lm;
#pragma unroll
        for (int nv = 0; nv < 4; ++nv)
            op[16*nv] = o[nv][i] * inv;
    }
}

} // namespace

extern "C" void kernel_launch(void* const* d_in, const int* in_sizes, int n_in,
                              void* d_out, int out_size, void* d_ws, size_t ws_size,
                              hipStream_t stream) {
    const float* q = (const float*)d_in[0];
    const float* k = (const float*)d_in[1];
    const float* v = (const float*)d_in[2];
    // d_in[3] (mask) is a pure function of (S,STRIDE,EXPR) reproduced in-kernel.
    float* out = (float*)d_out;
    dim3 grid(512), block(512);
    hipLaunchKernelGGL(sparse_attn22, grid, block, 0, stream, q, k, v, out);
}